// Round 4
// baseline (194.889 us; speedup 1.0000x reference)
//
#include <hip/hip_runtime.h>

#define CNT   2048
#define TPB   64          // one wave per block: no barriers, private vmcnt pipeline
#define NSEG  8           // 8 segments x 256 steps
// LDS layout (floats): [0,1024) gyro buf0 | [1024,2048) gyro buf1
//                      [2048,2304) ts buf0 | [2304,2560) ts buf1   -> 10240 B total
#define SMEM_F 2560

struct Q { float w, x, y, z; };

__device__ __forceinline__ Q qmul(const Q a, const Q b) {
    Q o;
    o.w = a.w*b.w - a.x*b.x - a.y*b.y - a.z*b.z;
    o.x = a.w*b.x + a.x*b.w + a.y*b.z - a.z*b.y;
    o.y = a.w*b.y - a.x*b.z + a.y*b.w + a.z*b.x;
    o.z = a.w*b.z + a.x*b.y - a.y*b.x + a.z*b.w;
    return o;
}
__device__ __forceinline__ Q qmul1(const Q a, const float bx, const float by, const float bz) {
    Q o;
    o.w = a.w - (a.x*bx + a.y*by + a.z*bz);
    o.x = a.x + (a.w*bx + a.y*bz - a.z*by);
    o.y = a.y + (a.w*by - a.x*bz + a.z*bx);
    o.z = a.z + (a.w*bz + a.x*by - a.y*bx);
    return o;
}

typedef __attribute__((address_space(1))) const void GAS;
typedef __attribute__((address_space(3))) void LAS;

__device__ __forceinline__ void cp16(const void* g, void* l) {
    // per-lane global addr (g already includes lane*16); LDS base wave-uniform
    __builtin_amdgcn_global_load_lds((GAS*)g, (LAS*)l, 16, 0, 0);
}
// simm16: vmcnt[3:0]|expcnt[6:4]|lgkmcnt[11:8]|vmcnt_hi[15:14]; lgkm/exp = no-wait
__device__ __forceinline__ void wait_vm5() { __builtin_amdgcn_s_waitcnt(0x0F75); }
__device__ __forceinline__ void wait_vm4() { __builtin_amdgcn_s_waitcnt(0x0F74); }
__device__ __forceinline__ void wait_vm0() { __builtin_amdgcn_s_waitcnt(0x0F70); }

// issue one segment's DMA: 4 gyro loads (3 for s==7) + 1 ts load = 5 (4 for s==7)
__device__ __forceinline__ void issue_seg(const char* grow, const char* trow,
                                          float* smem, int s, int lane) {
    char* gslot = (char*)(smem + ((s & 1) ? 1024 : 0));
    char* tslot = (char*)(smem + 2048 + ((s & 1) ? 256 : 0));
    const char* gs = grow + 3072 * s + 16 * lane;   // seg gyro base: sample 256s -> byte 3072s
    const char* tsr = trow + 1024 * s + 16 * lane;  // seg ts base: 1024s
    cp16(gs,        gslot);
    cp16(gs + 1024, gslot + 1024);
    cp16(gs + 2048, gslot + 2048);
    if (s != 7) cp16(gs + 3072, gslot + 3072);      // s<7 needs 3084 B (overrun stays in-row)
    cp16(tsr, tslot);                                // exactly 1024 B (in-row always)
}

__global__ __launch_bounds__(TPB) void quat_scan_kernel(
    const float* __restrict__ ts,    // (B, CNT)
    const float* __restrict__ gyro,  // (B, CNT, 3)
    const float* __restrict__ sq,    // (B, 4)
    const float* __restrict__ W1, const float* __restrict__ b1, const float* __restrict__ a1p,
    const float* __restrict__ W2, const float* __restrict__ b2, const float* __restrict__ a2p,
    float* __restrict__ out)         // (B, 4)
{
    __shared__ float smem[SMEM_F];   // 10240 B -> 16 blocks/CU

    const int b    = blockIdx.x;
    const int lane = threadIdx.x;    // 0..63

    const char* grow = (const char*)(gyro + (size_t)b * (CNT * 3));
    const char* trow = (const char*)(ts   + (size_t)b * CNT);

    // ---- uniform params -> SGPRs (SMEM/lgkmcnt: does not touch vmcnt)
    float w1[9], w2[9], bb1[3], bb2[3];
    #pragma unroll
    for (int i = 0; i < 9; ++i) { w1[i] = W1[i]; w2[i] = W2[i]; }
    #pragma unroll
    for (int i = 0; i < 3; ++i) { bb1[i] = b1[i]; bb2[i] = b2[i]; }
    const float a1 = a1p[0], a2 = a2p[0];

    // ---- ts segment-boundary samples ts[256*(k+1)], k=lane<8 — regular VMEM, issued
    // BEFORE the DMA pipeline (older strays retire first; wait counts stay valid).
    const float* trowf = (const float*)trow;
    int bidx = 256 * (lane + 1); if (bidx > 2047) bidx = 2047;
    const float tbound = trowf[bidx];

    auto gf = [&](const float* rg, int k, float& gx, float& gy, float& gz) {
        const float vx = rg[3*k + 0], vy = rg[3*k + 1], vz = rg[3*k + 2];
        float h0 = w1[0]*vx + w1[1]*vy + w1[2]*vz + bb1[0];
        float h1 = w1[3]*vx + w1[4]*vy + w1[5]*vz + bb1[1];
        float h2 = w1[6]*vx + w1[7]*vy + w1[8]*vz + bb1[2];
        h0 = h0 >= 0.0f ? h0 : a1 * h0;
        h1 = h1 >= 0.0f ? h1 : a1 * h1;
        h2 = h2 >= 0.0f ? h2 : a1 * h2;
        float u0 = w2[0]*h0 + w2[1]*h1 + w2[2]*h2 + bb2[0];
        float u1 = w2[3]*h0 + w2[4]*h1 + w2[5]*h2 + bb2[1];
        float u2 = w2[6]*h0 + w2[7]*h1 + w2[8]*h2 + bb2[2];
        u0 = u0 >= 0.0f ? u0 : a2 * u0;
        u1 = u1 >= 0.0f ? u1 : a2 * u1;
        u2 = u2 >= 0.0f ? u2 : a2 * u2;
        gx = u0 + vx; gy = u1 + vy; gz = u2 + vz;
    };

    Q qrow = {1.0f, 0.0f, 0.0f, 0.0f};

    // compute one segment from its LDS buffer; lane covers steps [256s+4l, 256s+4l+4)
    auto do_seg = [&](int s, bool fix_last) {
        const float* gb = smem + ((s & 1) ? 1024 : 0);
        const float* tb = smem + 2048 + ((s & 1) ? 256 : 0);

        float rg[16];
        const float4* gp4 = (const float4*)(gb + 12 * lane);  // byte 48*lane, 16B-aligned
        #pragma unroll
        for (int k = 0; k < 4; ++k) ((float4*)rg)[k] = gp4[k];

        float rt[5];
        *((float4*)rt) = *((const float4*)(tb + 4 * lane));
        float rt4 = tb[4 * lane + 4];                 // lane63 reads into next buf (fixed below)
        const float bnd = __shfl(tbound, s & 7);      // ts[256*(s+1)]
        rt[4] = (lane == 63) ? bnd : rt4;

        if (fix_last && lane == 63) {                 // step t=2047 doesn't exist: dq = identity
            rg[12] = rg[9]; rg[13] = rg[10]; rg[14] = rg[11];
            rt[4]  = rt[3];
        }

        Q P = {1.0f, 0.0f, 0.0f, 0.0f};
        float g0x, g0y, g0z;
        gf(rg, 0, g0x, g0y, g0z);
        #pragma unroll
        for (int j = 0; j < 4; ++j) {
            float g1x, g1y, g1z;
            gf(rg, j + 1, g1x, g1y, g1z);
            const float sc = 0.25f * (rt[j + 1] - rt[j]);
            P = qmul1(P, (g0x + g1x) * sc, (g0y + g1y) * sc, (g0z + g1z) * sc);
            g0x = g1x; g0y = g1y; g0z = g1z;
        }
        // normalize lane product (n2 >= 1), keeps reduction bounded
        const float n2  = P.w*P.w + P.x*P.x + P.y*P.y + P.z*P.z;
        const float inv = 1.0f / sqrtf(n2);
        P.w *= inv; P.x *= inv; P.y *= inv; P.z *= inv;

        // ordered 64-lane shuffle reduction: lane 0 = P_0 ⊗ ... ⊗ P_63
        #pragma unroll
        for (int sft = 1; sft < 64; sft <<= 1) {
            Q o;
            o.w = __shfl_down(P.w, sft);
            o.x = __shfl_down(P.x, sft);
            o.y = __shfl_down(P.y, sft);
            o.z = __shfl_down(P.z, sft);
            P = qmul(P, o);
        }
        qrow = qmul(qrow, P);   // only lane 0's value matters
    };

    // ---- software pipeline: depth-2 double buffer, waits never drain the prefetch
    issue_seg(grow, trow, smem, 0, lane);   // 5 loads
    issue_seg(grow, trow, smem, 1, lane);   // 5 loads
    for (int s = 0; s < 6; ++s) {
        wait_vm5();                         // seg s done; seg s+1 (5 loads) stays in flight
        do_seg(s, false);
        issue_seg(grow, trow, smem, s + 2, lane);   // s+2 <= 7 (s==5 issues 4 loads)
    }
    wait_vm4();                             // seg 6 done; seg 7 (4 loads) in flight
    do_seg(6, false);
    wait_vm0();                             // seg 7 done
    do_seg(7, true);

    // ---- epilogue (regular VMEM is fine now)
    if (lane == 0) {
        const float4 s0 = *((const float4*)(sq + (size_t)b * 4));
        const Q q0 = {s0.x, s0.y, s0.z, s0.w};
        Q qf = qmul(q0, qrow);
        const float n   = sqrtf(qf.w*qf.w + qf.x*qf.x + qf.y*qf.y + qf.z*qf.z);
        const float inv = 1.0f / fmaxf(n, 1e-12f);
        float4 o;
        o.x = qf.w * inv; o.y = qf.x * inv; o.z = qf.y * inv; o.w = qf.z * inv;
        *((float4*)(out + (size_t)b * 4)) = o;
    }
}

extern "C" void kernel_launch(void* const* d_in, const int* in_sizes, int n_in,
                              void* d_out, int out_size, void* d_ws, size_t ws_size,
                              hipStream_t stream) {
    const float* ts   = (const float*)d_in[0];
    const float* gyro = (const float*)d_in[1];
    const float* sq   = (const float*)d_in[2];
    const float* W1   = (const float*)d_in[3];
    const float* b1   = (const float*)d_in[4];
    const float* a1   = (const float*)d_in[5];
    const float* W2   = (const float*)d_in[6];
    const float* b2   = (const float*)d_in[7];
    const float* a2   = (const float*)d_in[8];
    float* out = (float*)d_out;

    const int B = in_sizes[0] / CNT;  // 4096

    quat_scan_kernel<<<B, TPB, 0, stream>>>(ts, gyro, sq, W1, b1, a1, W2, b2, a2, out);
}

// Round 5
// 192.451 us; speedup vs baseline: 1.0127x; 1.0127x over previous
//
#include <hip/hip_runtime.h>

#define CNT    2048
#define NSTEP  2047
#define TPB    256
#define BLOCKS 2048          // grid-stride persistent-ish; 16384 items / 8192 waves = 2 each
#define WPB    (TPB / 64)

struct Q { float w, x, y, z; };

__device__ __forceinline__ Q qmul(const Q a, const Q b) {
    Q o;
    o.w = a.w*b.w - a.x*b.x - a.y*b.y - a.z*b.z;
    o.x = a.w*b.x + a.x*b.w + a.y*b.z - a.z*b.y;
    o.y = a.w*b.y - a.x*b.z + a.y*b.w + a.z*b.x;
    o.z = a.w*b.z + a.x*b.y - a.y*b.x + a.z*b.w;
    return o;
}
__device__ __forceinline__ Q qmul1(const Q a, const float bx, const float by, const float bz) {
    Q o;
    o.w = a.w - (a.x*bx + a.y*by + a.z*bz);
    o.x = a.x + (a.w*bx + a.y*bz - a.z*by);
    o.y = a.y + (a.w*by - a.x*bz + a.z*bx);
    o.z = a.z + (a.w*bz + a.x*by - a.y*bx);
    return o;
}

// g(v) = prelu(W2 @ prelu(W1 @ v + b1, a1) + b2, a2) + v ; FAST = identity weights, zero bias
template<bool FAST>
__device__ __forceinline__ void gf_eval(const float* rg, int k,
        const float* w1, const float* bb1, float a1,
        const float* w2, const float* bb2, float a2,
        float& gx, float& gy, float& gz)
{
    const float vx = rg[3*k + 0], vy = rg[3*k + 1], vz = rg[3*k + 2];
    float h0, h1, h2;
    if (FAST) { h0 = vx; h1 = vy; h2 = vz; }
    else {
        h0 = w1[0]*vx + w1[1]*vy + w1[2]*vz + bb1[0];
        h1 = w1[3]*vx + w1[4]*vy + w1[5]*vz + bb1[1];
        h2 = w1[6]*vx + w1[7]*vy + w1[8]*vz + bb1[2];
    }
    h0 = h0 >= 0.0f ? h0 : a1 * h0;
    h1 = h1 >= 0.0f ? h1 : a1 * h1;
    h2 = h2 >= 0.0f ? h2 : a1 * h2;
    float u0, u1, u2;
    if (FAST) { u0 = h0; u1 = h1; u2 = h2; }
    else {
        u0 = w2[0]*h0 + w2[1]*h1 + w2[2]*h2 + bb2[0];
        u1 = w2[3]*h0 + w2[4]*h1 + w2[5]*h2 + bb2[1];
        u2 = w2[6]*h0 + w2[7]*h1 + w2[8]*h2 + bb2[2];
    }
    u0 = u0 >= 0.0f ? u0 : a2 * u0;
    u1 = u1 >= 0.0f ? u1 : a2 * u1;
    u2 = u2 >= 0.0f ? u2 : a2 * u2;
    gx = u0 + vx; gy = u1 + vy; gz = u2 + vz;
}

// ordered product of this lane's 8 steps, then ordered 64-lane shuffle reduction.
template<bool FAST>
__device__ __forceinline__ Q seg_product(const float* rg, const float* rt,
        const float* w1, const float* bb1, float a1,
        const float* w2, const float* bb2, float a2)
{
    Q P = {1.0f, 0.0f, 0.0f, 0.0f};
    float g0x, g0y, g0z;
    gf_eval<FAST>(rg, 0, w1, bb1, a1, w2, bb2, a2, g0x, g0y, g0z);
    #pragma unroll
    for (int j = 0; j < 8; ++j) {
        float g1x, g1y, g1z;
        gf_eval<FAST>(rg, j + 1, w1, bb1, a1, w2, bb2, a2, g1x, g1y, g1z);
        const float sc = 0.25f * (rt[j + 1] - rt[j]);
        P = qmul1(P, (g0x + g1x) * sc, (g0y + g1y) * sc, (g0z + g1z) * sc);
        g0x = g1x; g0y = g1y; g0z = g1z;
    }
    // normalize lane product (n2 >= 1; keeps tree bounded)
    const float n2  = P.w*P.w + P.x*P.x + P.y*P.y + P.z*P.z;
    const float inv = 1.0f / sqrtf(n2);
    P.w *= inv; P.x *= inv; P.y *= inv; P.z *= inv;
    // ordered reduction: lane 0 ends with P_0 ⊗ ... ⊗ P_63
    #pragma unroll
    for (int sft = 1; sft < 64; sft <<= 1) {
        Q o;
        o.w = __shfl_down(P.w, sft);
        o.x = __shfl_down(P.x, sft);
        o.y = __shfl_down(P.y, sft);
        o.z = __shfl_down(P.z, sft);
        P = qmul(P, o);
    }
    return P;
}

__global__ __launch_bounds__(TPB) void pass1_kernel(
    const float* __restrict__ ts,    // (B, CNT)
    const float* __restrict__ gyro,  // (B, CNT, 3)
    const float* __restrict__ W1, const float* __restrict__ b1, const float* __restrict__ a1p,
    const float* __restrict__ W2, const float* __restrict__ b2, const float* __restrict__ a2p,
    float4* __restrict__ ws,         // (B*4) partial quats
    int nitems)
{
    const int lane = threadIdx.x & 63;
    const int wgid = blockIdx.x * WPB + (threadIdx.x >> 6);
    const int nw   = gridDim.x * WPB;

    // uniform params (scalar-cached)
    float w1[9], w2[9], bb1[3], bb2[3];
    #pragma unroll
    for (int i = 0; i < 9; ++i) { w1[i] = W1[i]; w2[i] = W2[i]; }
    #pragma unroll
    for (int i = 0; i < 3; ++i) { bb1[i] = b1[i]; bb2[i] = b2[i]; }
    const float a1 = a1p[0], a2 = a2p[0];

    // identity fast-path flag (uniform). Fast path is exactly equivalent when flag holds.
    float dev = 0.0f;
    #pragma unroll
    for (int i = 0; i < 9; ++i) {
        const float id = (i == 0 || i == 4 || i == 8) ? 1.0f : 0.0f;
        dev += fabsf(w1[i] - id) + fabsf(w2[i] - id);
    }
    #pragma unroll
    for (int i = 0; i < 3; ++i) dev += fabsf(bb1[i]) + fabsf(bb2[i]);
    const bool fast = (dev == 0.0f);

    // item = (row r, seg s): lane covers steps [512s + 8*lane, +8)
    auto loadit = [&](int item, float* rg, float* rt) {
        const int r = item >> 2, s = item & 3;
        const bool last = (s == 3) && (lane == 63);   // contains the nonexistent step t=2047
        // gyro samples 512s+8l .. +9 : float index 1536s+24l -> float4 index 384s+6l (aligned)
        const float4* gp = (const float4*)(gyro + (size_t)r * (CNT * 3)) + (384 * s + 6 * lane);
        #pragma unroll
        for (int k = 0; k < 6; ++k) ((float4*)rg)[k] = gp[k];
        ((float4*)rg)[6] = last ? make_float4(0.f, 0.f, 0.f, 0.f) : gp[6];
        // ts samples 512s+8l .. +8
        const float* trow = ts + (size_t)r * CNT + (512 * s + 8 * lane);
        ((float4*)rt)[0] = ((const float4*)trow)[0];
        ((float4*)rt)[1] = ((const float4*)trow)[1];
        rt[8] = last ? rt[7] : trow[8];               // pad step -> dt = 0 -> identity dq
    };

    float rgA[28], rtA[9];
    int item = wgid;
    if (item < nitems) loadit(item, rgA, rtA);

    for (; item < nitems; item += nw) {
        const int nxt = item + nw;
        float rgB[28], rtB[9];
        if (nxt < nitems) loadit(nxt, rgB, rtB);      // prefetch stays in flight during compute

        Q P = fast ? seg_product<true >(rgA, rtA, w1, bb1, a1, w2, bb2, a2)
                   : seg_product<false>(rgA, rtA, w1, bb1, a1, w2, bb2, a2);
        if (lane == 0) ws[item] = make_float4(P.w, P.x, P.y, P.z);

        #pragma unroll
        for (int i = 0; i < 28; ++i) rgA[i] = rgB[i];
        #pragma unroll
        for (int i = 0; i < 9; ++i)  rtA[i] = rtB[i];
    }
}

__global__ __launch_bounds__(TPB) void pass2_kernel(
    const float4* __restrict__ ws,   // (B*4) partials in segment order
    const float*  __restrict__ sq,   // (B, 4)
    float* __restrict__ out, int B)
{
    const int r = blockIdx.x * blockDim.x + threadIdx.x;
    if (r >= B) return;
    float4 p0 = ws[4*r + 0];
    Q acc = {p0.x, p0.y, p0.z, p0.w};
    #pragma unroll
    for (int k = 1; k < 4; ++k) {
        const float4 pk = ws[4*r + k];
        const Q qk = {pk.x, pk.y, pk.z, pk.w};
        acc = qmul(acc, qk);
    }
    const float4 s0 = ((const float4*)sq)[r];
    const Q q0 = {s0.x, s0.y, s0.z, s0.w};
    Q qf = qmul(q0, acc);
    const float n   = sqrtf(qf.w*qf.w + qf.x*qf.x + qf.y*qf.y + qf.z*qf.z);
    const float inv = 1.0f / fmaxf(n, 1e-12f);
    float4 o;
    o.x = qf.w * inv; o.y = qf.x * inv; o.z = qf.y * inv; o.w = qf.z * inv;
    ((float4*)out)[r] = o;
}

extern "C" void kernel_launch(void* const* d_in, const int* in_sizes, int n_in,
                              void* d_out, int out_size, void* d_ws, size_t ws_size,
                              hipStream_t stream) {
    const float* ts   = (const float*)d_in[0];
    const float* gyro = (const float*)d_in[1];
    const float* sq   = (const float*)d_in[2];
    const float* W1   = (const float*)d_in[3];
    const float* b1   = (const float*)d_in[4];
    const float* a1   = (const float*)d_in[5];
    const float* W2   = (const float*)d_in[6];
    const float* b2   = (const float*)d_in[7];
    const float* a2   = (const float*)d_in[8];
    float* out = (float*)d_out;

    const int B      = in_sizes[0] / CNT;   // 4096
    const int nitems = B * 4;
    float4* ws = (float4*)d_ws;             // nitems * 16 B = 256 KB

    pass1_kernel<<<BLOCKS, TPB, 0, stream>>>(ts, gyro, W1, b1, a1, W2, b2, a2, ws, nitems);
    pass2_kernel<<<(B + TPB - 1) / TPB, TPB, 0, stream>>>(ws, sq, out, B);
}